// Round 1
// baseline (682.284 us; speedup 1.0000x reference)
//
#include <hip/hip_runtime.h>
#include <math.h>

#define HW 9216
#define C 64
#define BATCH 2
#define K 7
#define NCHUNK 4
#define CHUNK_N (HW / NCHUNK)            // 2304
#define TILES_PER_CHUNK (CHUNK_N / 64)   // 36

// ---------------- kernel 1: normalize + transpose ----------------
// Xn[b][c][m] = x / ||x_col||,  XT[b][m][c] = x (unnormalized, transposed)
__global__ __launch_bounds__(256) void k_norm(const float* __restrict__ x,
                                              float* __restrict__ Xn,
                                              float* __restrict__ XT) {
    int b = blockIdx.y;
    int m0 = blockIdx.x * 64;
    __shared__ float T[64 * 65];   // [c][m] padded
    __shared__ float psum[4][64];
    __shared__ float inv[64];
    const float* xb = x + (size_t)b * C * HW;
    int tid = threadIdx.x;

    for (int r = 0; r < 16; ++r) {
        int idx = r * 256 + tid;
        int c = idx >> 6, mm = idx & 63;
        T[c * 65 + mm] = xb[c * HW + m0 + mm];
    }
    __syncthreads();
    int ml = tid & 63, part = tid >> 6;
    float s = 0.f;
    for (int c = part * 16; c < part * 16 + 16; ++c) {
        float v = T[c * 65 + ml];
        s += v * v;
    }
    psum[part][ml] = s;
    __syncthreads();
    if (tid < 64) {
        float tot = psum[0][tid] + psum[1][tid] + psum[2][tid] + psum[3][tid];
        inv[tid] = 1.0f / sqrtf(tot);
    }
    __syncthreads();
    float* Xnb = Xn + (size_t)b * C * HW;
    for (int r = 0; r < 16; ++r) {
        int idx = r * 256 + tid;
        int c = idx >> 6, mm = idx & 63;
        Xnb[c * HW + m0 + mm] = T[c * 65 + mm] * inv[mm];
    }
    float* XTb = XT + (size_t)b * HW * C;
    for (int r = 0; r < 16; ++r) {
        int idx = r * 256 + tid;
        int row = idx >> 6, c = idx & 63;   // row = local m, coalesced write
        XTb[(size_t)(m0 + row) * C + c] = T[c * 65 + row];
    }
}

// ---------------- kernel 1b: transpose W -> Wt[k][i][o] ----------------
__global__ void k_wt(const float* __restrict__ W, float* __restrict__ Wt) {
    int idx = blockIdx.x * 256 + threadIdx.x;
    if (idx < C * C * K) {
        int k = idx / (C * C);
        int rem = idx - k * (C * C);
        int i = rem >> 6, o = rem & 63;
        Wt[idx] = W[(o * C + i) * K + k];
    }
}

// ---------------- kernel 2: tiled scores + fused per-row top-7 ----------------
// grid (144 row-tiles, NCHUNK, BATCH), 256 threads.
__global__ __launch_bounds__(256) void k_score(const float* __restrict__ Xn,
                                               float* __restrict__ pvals,
                                               int* __restrict__ pidx) {
    int rowTile = blockIdx.x, chunk = blockIdx.y, b = blockIdx.z;
    int m0 = rowTile * 64;
    const float* Xb = Xn + (size_t)b * C * HW;

    __shared__ float Am[64 * 68];   // [c][m]
    __shared__ float Bn[64 * 68];   // [c][n]
    __shared__ float Sc[64 * 68];   // [m][n] score tile

    int tid = threadIdx.x;
    int tx = tid & 15, ty = tid >> 4;
    int row = tid & 63, q = tid >> 6;

    for (int r = 0; r < 16; ++r) {
        int idx = r * 256 + tid;
        int c = idx >> 6, mm = idx & 63;
        Am[c * 68 + mm] = Xb[c * HW + m0 + mm];
    }

    float tv[7];
    int ti[7];
#pragma unroll
    for (int j = 0; j < 7; ++j) { tv[j] = -2.0f; ti[j] = 0x7fffffff; }

    for (int t = 0; t < TILES_PER_CHUNK; ++t) {
        int n0 = chunk * CHUNK_N + t * 64;
        __syncthreads();   // previous scan done (Sc/Bn reusable); also covers Am on t=0
        for (int r = 0; r < 16; ++r) {
            int idx = r * 256 + tid;
            int c = idx >> 6, nn = idx & 63;
            Bn[c * 68 + nn] = Xb[c * HW + n0 + nn];
        }
        __syncthreads();

        float acc[4][4];
#pragma unroll
        for (int i = 0; i < 4; ++i)
#pragma unroll
            for (int j = 0; j < 4; ++j) acc[i][j] = 0.f;

#pragma unroll 16
        for (int k = 0; k < 64; ++k) {
            float4 a = *(const float4*)&Am[k * 68 + ty * 4];
            float4 bv = *(const float4*)&Bn[k * 68 + tx * 4];
            acc[0][0] += a.x * bv.x; acc[0][1] += a.x * bv.y; acc[0][2] += a.x * bv.z; acc[0][3] += a.x * bv.w;
            acc[1][0] += a.y * bv.x; acc[1][1] += a.y * bv.y; acc[1][2] += a.y * bv.z; acc[1][3] += a.y * bv.w;
            acc[2][0] += a.z * bv.x; acc[2][1] += a.z * bv.y; acc[2][2] += a.z * bv.z; acc[2][3] += a.z * bv.w;
            acc[3][0] += a.w * bv.x; acc[3][1] += a.w * bv.y; acc[3][2] += a.w * bv.z; acc[3][3] += a.w * bv.w;
        }
#pragma unroll
        for (int i = 0; i < 4; ++i) {
            float4 r4;
            r4.x = acc[i][0]; r4.y = acc[i][1]; r4.z = acc[i][2]; r4.w = acc[i][3];
            *(float4*)&Sc[(ty * 4 + i) * 68 + tx * 4] = r4;
        }
        __syncthreads();

        // scan: thread (row, q) scans 16 columns of its row
#pragma unroll
        for (int j = 0; j < 16; ++j) {
            int col = q * 16 + j;
            float v = Sc[row * 68 + col];
            if (v > tv[6]) {
                tv[6] = v; ti[6] = n0 + col;
#pragma unroll
                for (int s = 5; s >= 0; --s) {
                    if (tv[s + 1] > tv[s]) {
                        float a = tv[s]; tv[s] = tv[s + 1]; tv[s + 1] = a;
                        int bI = ti[s]; ti[s] = ti[s + 1]; ti[s + 1] = bI;
                    }
                }
            }
        }
    }

    // in-block merge of the 4 quarter-lists per row
    __syncthreads();
    float* mv = Am;
    int* mi = (int*)Bn;
#pragma unroll
    for (int j = 0; j < 7; ++j) {
        mv[row * 28 + q * 7 + j] = tv[j];
        mi[row * 28 + q * 7 + j] = ti[j];
    }
    __syncthreads();
    if (tid < 64) {
        int gm = (b * NCHUNK + chunk) * HW + m0 + tid;
        for (int s = 0; s < 7; ++s) {
            float bv = -3.0f; int bi = 0x7fffffff; int bp = 0;
            for (int j = 0; j < 28; ++j) {
                float vv = mv[tid * 28 + j];
                int ii = mi[tid * 28 + j];
                if (vv > bv || (vv == bv && ii < bi)) { bv = vv; bi = ii; bp = j; }
            }
            mv[tid * 28 + bp] = -3.0f;
            pvals[(size_t)gm * 7 + s] = bv;
            pidx[(size_t)gm * 7 + s] = bi;
        }
    }
}

// ---------------- kernel 3: merge NCHUNK partial lists -> final sorted top-7 ----------------
__global__ void k_merge(const float* __restrict__ pvals, const int* __restrict__ pidx,
                        float* __restrict__ fvals, int* __restrict__ fidx) {
    int g = blockIdx.x * 256 + threadIdx.x;   // over BATCH*HW
    if (g >= BATCH * HW) return;
    int b = g / HW, m = g - b * HW;
    unsigned consumed = 0;
    for (int s = 0; s < 7; ++s) {
        float bv = -3.0f; int bi = 0x7fffffff; int bp = 0;
#pragma unroll
        for (int j = 0; j < 28; ++j) {
            if (consumed & (1u << j)) continue;
            int ch = j / 7, jj = j - ch * 7;
            float vv = pvals[((size_t)(b * NCHUNK + ch) * HW + m) * 7 + jj];
            int ii = pidx[((size_t)(b * NCHUNK + ch) * HW + m) * 7 + jj];
            if (vv > bv || (vv == bv && ii < bi)) { bv = vv; bi = ii; bp = j; }
        }
        consumed |= (1u << bp);
        fvals[(size_t)g * 7 + s] = bv;
        fidx[(size_t)g * 7 + s] = bi;
    }
}

// ---------------- kernel 4: gather + conv contraction + bias + relu ----------------
// grid (576, BATCH): 16 m per block; thread = (oq 0..15, ml 0..15)
__global__ __launch_bounds__(256) void k_out(const float* __restrict__ XT,
                                             const float* __restrict__ Wt,
                                             const float* __restrict__ fvals,
                                             const int* __restrict__ fidx,
                                             const float* __restrict__ bias,
                                             float* __restrict__ out) {
    int b = blockIdx.y;
    int m0 = blockIdx.x * 16;
    __shared__ float Wk[64 * 64];   // [i][o]
    __shared__ float Gw[16 * 64];   // [ml][i]
    int tid = threadIdx.x;
    int oq = tid & 15, ml = tid >> 4;
    float acc[4] = {0.f, 0.f, 0.f, 0.f};

    for (int k = 0; k < K; ++k) {
        __syncthreads();
        for (int r = 0; r < 16; ++r) Wk[r * 256 + tid] = Wt[k * 4096 + r * 256 + tid];
        {
            int pos = tid * 4;
            int m2 = pos >> 6, i0 = pos & 63;   // m2 == ml
            int gm = (b * HW + m0 + m2) * 7 + k;
            int n = fidx[gm];
            float vv = fvals[gm];
            float4 g = *(const float4*)&XT[((size_t)b * HW + n) * C + i0];
            float4 gw;
            gw.x = g.x * vv; gw.y = g.y * vv; gw.z = g.z * vv; gw.w = g.w * vv;
            *(float4*)&Gw[m2 * 64 + i0] = gw;
        }
        __syncthreads();
#pragma unroll 16
        for (int i = 0; i < 64; ++i) {
            float4 w = *(const float4*)&Wk[i * 64 + oq * 4];
            float g = Gw[ml * 64 + i];
            acc[0] += g * w.x; acc[1] += g * w.y; acc[2] += g * w.z; acc[3] += g * w.w;
        }
    }
    int m = m0 + ml;
#pragma unroll
    for (int j = 0; j < 4; ++j) {
        int o = oq * 4 + j;
        float v = acc[j] + bias[o];
        out[((size_t)b * C + o) * HW + m] = v > 0.f ? v : 0.f;
    }
}

extern "C" void kernel_launch(void* const* d_in, const int* in_sizes, int n_in,
                              void* d_out, int out_size, void* d_ws, size_t ws_size,
                              hipStream_t stream) {
    const float* x = (const float*)d_in[0];
    const float* W = (const float*)d_in[1];
    const float* bias = (const float*)d_in[2];
    float* out = (float*)d_out;

    float* ws = (float*)d_ws;
    float* Xn = ws;                                  // B*C*HW
    float* XT = Xn + (size_t)BATCH * C * HW;         // B*HW*C
    float* Wt = XT + (size_t)BATCH * C * HW;         // K*C*C
    float* pvals = Wt + C * C * K;                   // B*NCHUNK*HW*K
    int* pidx = (int*)(pvals + (size_t)BATCH * NCHUNK * HW * K);
    float* fvals = (float*)(pidx + (size_t)BATCH * NCHUNK * HW * K);
    int* fidx = (int*)(fvals + (size_t)BATCH * HW * K);

    k_norm<<<dim3(HW / 64, BATCH), 256, 0, stream>>>(x, Xn, XT);
    k_wt<<<dim3((C * C * K + 255) / 256), 256, 0, stream>>>(W, Wt);
    k_score<<<dim3(HW / 64, NCHUNK, BATCH), 256, 0, stream>>>(Xn, pvals, pidx);
    k_merge<<<dim3((BATCH * HW + 255) / 256), 256, 0, stream>>>(pvals, pidx, fvals, fidx);
    k_out<<<dim3(HW / 16, BATCH), 256, 0, stream>>>(XT, Wt, fvals, fidx, bias, out);
}

// Round 2
// 352.247 us; speedup vs baseline: 1.9369x; 1.9369x over previous
//
#include <hip/hip_runtime.h>
#include <math.h>

#define HW 9216
#define C 64
#define BATCH 2
#define K 7
#define NCH 8
#define CHUNK 1152           // HW/NCH
#define NSTEP 36             // CHUNK/32
#define NCAND 72             // NCH*9

typedef __attribute__((ext_vector_type(8))) short bf16x8;
typedef __attribute__((ext_vector_type(16))) float f32x16;

#define GLOAD_LDS(gp, lp) __builtin_amdgcn_global_load_lds( \
    (const __attribute__((address_space(1))) unsigned int*)(gp), \
    (__attribute__((address_space(3))) unsigned int*)(lp), 16, 0, 0)

// ---------------- kernel 1: normalize + transpose + bf16 ----------------
// XT[b][m][c] = x (unnorm, transposed), Xhi[b][m][c] = bf16(normalized), invn[b][m]
__global__ __launch_bounds__(256) void k_norm(const float* __restrict__ x,
                                              float* __restrict__ XT,
                                              unsigned short* __restrict__ Xhi,
                                              float* __restrict__ invn) {
    int b = blockIdx.y, m0 = blockIdx.x * 64, tid = threadIdx.x;
    __shared__ float T[64 * 65];
    __shared__ float ps[4][64];
    __shared__ float inv[64];
    const float* xb = x + (size_t)b * C * HW;
    for (int r = 0; r < 16; ++r) {
        int idx = r * 256 + tid; int c = idx >> 6, mm = idx & 63;
        T[c * 65 + mm] = xb[(size_t)c * HW + m0 + mm];
    }
    __syncthreads();
    int ml = tid & 63, part = tid >> 6;
    float s = 0.f;
    for (int c = part * 16; c < part * 16 + 16; ++c) { float v = T[c * 65 + ml]; s += v * v; }
    ps[part][ml] = s;
    __syncthreads();
    if (tid < 64) {
        float tot = ps[0][tid] + ps[1][tid] + ps[2][tid] + ps[3][tid];
        float iv = 1.0f / sqrtf(tot);
        inv[tid] = iv;
        invn[(size_t)b * HW + m0 + tid] = iv;
    }
    __syncthreads();
    for (int r = 0; r < 16; ++r) {
        int idx = r * 256 + tid; int row = idx >> 6, c = idx & 63;
        float uv = T[c * 65 + row];
        XT[((size_t)b * HW + m0 + row) * C + c] = uv;
        float nv = uv * inv[row];
        unsigned u = __float_as_uint(nv);
        unsigned rr = u + 0x7fffu + ((u >> 16) & 1u);   // RNE to bf16
        Xhi[((size_t)b * HW + m0 + row) * C + c] = (unsigned short)(rr >> 16);
    }
}

// ---------------- kernel 1b: transpose W -> Wt[k][i][o] ----------------
__global__ void k_wt(const float* __restrict__ W, float* __restrict__ Wt) {
    int idx = blockIdx.x * 256 + threadIdx.x;
    if (idx < C * C * K) {
        int k = idx / (C * C);
        int rem = idx - k * (C * C);
        int i = rem >> 6, o = rem & 63;
        Wt[idx] = W[(o * C + i) * K + k];
    }
}

// ---------------- kernel 2: MFMA approx scores + in-register per-row top-9 ----------------
// grid (72, NCH, BATCH), 256 threads (4 waves x 32 m-cols each).
// Swapped operands: A = n-panel (staged LDS), B = m-panel (regs) -> lane's scores all for its m.
__global__ __launch_bounds__(256) void k_score(const unsigned short* __restrict__ Xhi,
                                               int* __restrict__ candi) {
    int mg = blockIdx.x, chunk = blockIdx.y, b = blockIdx.z;
    int tid = threadIdx.x;
    int w = tid >> 6, l = tid & 63;
    int lr = l & 31, lh = l >> 5;
    int m = mg * 128 + w * 32 + lr;
    const char* Xb = (const char*)(Xhi + (size_t)b * HW * C);   // 128B rows

    __shared__ __align__(16) char tiles[2][4096];
    __shared__ float MV[4][32][18];
    __shared__ int   MI[4][32][18];

    // B-frags (m operand), loaded once
    bf16x8 bf[4];
#pragma unroll
    for (int t = 0; t < 4; ++t)
        bf[t] = *(const bf16x8*)(Xb + (size_t)m * 128 + t * 32 + lh * 16);

    int swsrc = (tid * 16) ^ (((tid >> 3) & 7) << 4);   // pre-swizzled source offset
    int nC = chunk * CHUNK;

    // prologue stage (step 0)
    GLOAD_LDS(Xb + (size_t)nC * 128 + swsrc, &tiles[0][w * 1024]);
    __syncthreads();

    float tv[9]; int ti[9];
#pragma unroll
    for (int j = 0; j < 9; ++j) { tv[j] = -2.0f; ti[j] = 0; }

    for (int s = 0; s < NSTEP; ++s) {
        if (s + 1 < NSTEP)
            GLOAD_LDS(Xb + (size_t)(nC + (s + 1) * 32) * 128 + swsrc,
                      &tiles[(s + 1) & 1][w * 1024]);
        const char* tile = tiles[s & 1];
        f32x16 acc = {0.f,0.f,0.f,0.f,0.f,0.f,0.f,0.f,0.f,0.f,0.f,0.f,0.f,0.f,0.f,0.f};
#pragma unroll
        for (int t = 0; t < 4; ++t) {
            int o = t * 32 + lh * 16;
            bf16x8 af = *(const bf16x8*)(tile + lr * 128 + (o ^ ((lr & 7) << 4)));
            acc = __builtin_amdgcn_mfma_f32_32x32x16_bf16(af, bf[t], acc, 0, 0, 0);
        }
        int n0 = nC + s * 32;
#pragma unroll
        for (int r = 0; r < 16; ++r) {
            float v = acc[r];
            if (v > tv[8]) {
                int nn = n0 + (r & 3) + 8 * (r >> 2) + 4 * lh;
                tv[8] = v; ti[8] = nn;
#pragma unroll
                for (int q = 7; q >= 0; --q) {
                    if (tv[q + 1] > tv[q]) {
                        float fv = tv[q]; tv[q] = tv[q + 1]; tv[q + 1] = fv;
                        int iv = ti[q]; ti[q] = ti[q + 1]; ti[q + 1] = iv;
                    }
                }
            }
        }
        __syncthreads();   // drains stage(s+1) issue->complete; buf[s&1] reads done
    }

    // tail: merge the two half-lane sorted 9-lists per row -> chunk top-9 indices
#pragma unroll
    for (int j = 0; j < 9; ++j) { MV[w][lr][lh * 9 + j] = tv[j]; MI[w][lr][lh * 9 + j] = ti[j]; }
    __syncthreads();
    if (lh == 0) {
        const float* av = MV[w][lr];
        const int*   ai = MI[w][lr];
        int i = 0, j = 9;
        size_t base = ((size_t)(b * HW + m) * NCH + chunk) * 9;
        for (int sO = 0; sO < 9; ++sO) {
            bool takeA;
            if (i >= 9) takeA = false;
            else if (j >= 18) takeA = true;
            else takeA = (av[i] > av[j]) || (av[i] == av[j] && ai[i] < ai[j]);
            if (takeA) { candi[base + sO] = ai[i]; ++i; }
            else       { candi[base + sO] = ai[j]; ++j; }
        }
    }
}

// ---------------- kernel 3: exact fp32 rescore of 72 candidates + top-7 ----------------
// one wave per row
__global__ __launch_bounds__(256) void k_rescore(const float* __restrict__ XT,
                                                 const float* __restrict__ invn,
                                                 const int* __restrict__ candi,
                                                 float* __restrict__ fvals,
                                                 int* __restrict__ fidx) {
    int g = blockIdx.x * 4 + (threadIdx.x >> 6);
    int l = threadIdx.x & 63;
    int b = g / HW, m = g - b * HW;
    const float* Xb = XT + (size_t)b * HW * C;
    const float4* xm = (const float4*)(Xb + (size_t)m * C);
    float vm = invn[g];

    float sv[2]; int si[2];
    {
        int ci = candi[(size_t)g * NCAND + l];
        const float4* xn = (const float4*)(Xb + (size_t)ci * C);
        float4 a = {0.f, 0.f, 0.f, 0.f};
#pragma unroll
        for (int c4 = 0; c4 < 16; ++c4) {
            float4 p = xm[c4], q = xn[c4];
            a.x += p.x * q.x; a.y += p.y * q.y; a.z += p.z * q.z; a.w += p.w * q.w;
        }
        sv[0] = (a.x + a.y + a.z + a.w) * vm * invn[(size_t)b * HW + ci];
        si[0] = ci;
    }
    if (l < 8) {
        int ci = candi[(size_t)g * NCAND + 64 + l];
        const float4* xn = (const float4*)(Xb + (size_t)ci * C);
        float4 a = {0.f, 0.f, 0.f, 0.f};
#pragma unroll
        for (int c4 = 0; c4 < 16; ++c4) {
            float4 p = xm[c4], q = xn[c4];
            a.x += p.x * q.x; a.y += p.y * q.y; a.z += p.z * q.z; a.w += p.w * q.w;
        }
        sv[1] = (a.x + a.y + a.z + a.w) * vm * invn[(size_t)b * HW + ci];
        si[1] = ci;
    } else { sv[1] = -1e30f; si[1] = 0x7fffffff; }

    for (int s = 0; s < 7; ++s) {
        bool p0 = (sv[0] > sv[1]) || (sv[0] == sv[1] && si[0] < si[1]);
        float bv = p0 ? sv[0] : sv[1];
        int   bi = p0 ? si[0] : si[1];
#pragma unroll
        for (int d = 1; d < 64; d <<= 1) {
            float ov = __shfl_xor(bv, d, 64);
            int   oi = __shfl_xor(bi, d, 64);
            if (ov > bv || (ov == bv && oi < bi)) { bv = ov; bi = oi; }
        }
        if (l == 0) { fvals[(size_t)g * 7 + s] = bv; fidx[(size_t)g * 7 + s] = bi; }
        if (si[0] == bi) sv[0] = -1e30f;
        if (si[1] == bi) sv[1] = -1e30f;
    }
}

// ---------------- kernel 4: gather + conv contraction + bias + relu ----------------
__global__ __launch_bounds__(256) void k_out(const float* __restrict__ XT,
                                             const float* __restrict__ Wt,
                                             const float* __restrict__ fvals,
                                             const int* __restrict__ fidx,
                                             const float* __restrict__ bias,
                                             float* __restrict__ out) {
    int b = blockIdx.y;
    int m0 = blockIdx.x * 16;
    __shared__ float Wk[64 * 64];   // [i][o]
    __shared__ float Gw[16 * 64];   // [ml][i]
    int tid = threadIdx.x;
    int oq = tid & 15, ml = tid >> 4;
    float acc[4] = {0.f, 0.f, 0.f, 0.f};

    for (int k = 0; k < K; ++k) {
        __syncthreads();
        for (int r = 0; r < 16; ++r) Wk[r * 256 + tid] = Wt[k * 4096 + r * 256 + tid];
        {
            int pos = tid * 4;
            int m2 = pos >> 6, i0 = pos & 63;
            int gm = (b * HW + m0 + m2) * 7 + k;
            int n = fidx[gm];
            float vv = fvals[gm];
            float4 g = *(const float4*)&XT[((size_t)b * HW + n) * C + i0];
            float4 gw;
            gw.x = g.x * vv; gw.y = g.y * vv; gw.z = g.z * vv; gw.w = g.w * vv;
            *(float4*)&Gw[m2 * 64 + i0] = gw;
        }
        __syncthreads();
#pragma unroll 16
        for (int i = 0; i < 64; ++i) {
            float4 w = *(const float4*)&Wk[i * 64 + oq * 4];
            float g = Gw[ml * 64 + i];
            acc[0] += g * w.x; acc[1] += g * w.y; acc[2] += g * w.z; acc[3] += g * w.w;
        }
    }
    int m = m0 + ml;
#pragma unroll
    for (int j = 0; j < 4; ++j) {
        int o = oq * 4 + j;
        float v = acc[j] + bias[o];
        out[((size_t)b * C + o) * HW + m] = v > 0.f ? v : 0.f;
    }
}

extern "C" void kernel_launch(void* const* d_in, const int* in_sizes, int n_in,
                              void* d_out, int out_size, void* d_ws, size_t ws_size,
                              hipStream_t stream) {
    const float* x = (const float*)d_in[0];
    const float* W = (const float*)d_in[1];
    const float* bias = (const float*)d_in[2];
    float* out = (float*)d_out;

    float* ws = (float*)d_ws;
    float* XT = ws;                                        // B*HW*C
    unsigned short* Xhi = (unsigned short*)(XT + (size_t)BATCH * HW * C);   // B*HW*C bf16
    float* invn = (float*)(Xhi + (size_t)BATCH * HW * C);  // B*HW
    float* Wt = invn + (size_t)BATCH * HW;                 // K*C*C
    int* candi = (int*)(Wt + C * C * K);                   // B*HW*NCAND
    float* fvals = (float*)(candi + (size_t)BATCH * HW * NCAND);
    int* fidx = (int*)(fvals + (size_t)BATCH * HW * K);

    k_norm<<<dim3(HW / 64, BATCH), 256, 0, stream>>>(x, XT, Xhi, invn);
    k_wt<<<dim3((C * C * K + 255) / 256), 256, 0, stream>>>(W, Wt);
    k_score<<<dim3(HW / 128, NCH, BATCH), 256, 0, stream>>>(Xhi, candi);
    k_rescore<<<dim3(BATCH * HW / 4), 256, 0, stream>>>(XT, invn, candi, fvals, fidx);
    k_out<<<dim3(HW / 16, BATCH), 256, 0, stream>>>(XT, Wt, fvals, fidx, bias, out);
}

// Round 3
// 264.028 us; speedup vs baseline: 2.5841x; 1.3341x over previous
//
#include <hip/hip_runtime.h>
#include <math.h>

#define HW 9216
#define C 64
#define BATCH 2
#define K 7
#define NCH 8
#define CHUNK 1152           // HW/NCH
#define NSTEP 36             // CHUNK/32
#define NCAND 72             // NCH*9

typedef __attribute__((ext_vector_type(8))) short bf16x8;
typedef __attribute__((ext_vector_type(16))) float f32x16;

#define GLOAD_LDS(gp, lp) __builtin_amdgcn_global_load_lds( \
    (const __attribute__((address_space(1))) unsigned int*)(gp), \
    (__attribute__((address_space(3))) unsigned int*)(lp), 16, 0, 0)

// ---------------- kernel 1: normalize + transpose + bf16 ----------------
__global__ __launch_bounds__(256) void k_norm(const float* __restrict__ x,
                                              float* __restrict__ XT,
                                              unsigned short* __restrict__ Xhi,
                                              float* __restrict__ invn) {
    int b = blockIdx.y, m0 = blockIdx.x * 64, tid = threadIdx.x;
    __shared__ float T[64 * 65];
    __shared__ float ps[4][64];
    __shared__ float inv[64];
    const float* xb = x + (size_t)b * C * HW;
    for (int r = 0; r < 16; ++r) {
        int idx = r * 256 + tid; int c = idx >> 6, mm = idx & 63;
        T[c * 65 + mm] = xb[(size_t)c * HW + m0 + mm];
    }
    __syncthreads();
    int ml = tid & 63, part = tid >> 6;
    float s = 0.f;
    for (int c = part * 16; c < part * 16 + 16; ++c) { float v = T[c * 65 + ml]; s += v * v; }
    ps[part][ml] = s;
    __syncthreads();
    if (tid < 64) {
        float tot = ps[0][tid] + ps[1][tid] + ps[2][tid] + ps[3][tid];
        float iv = 1.0f / sqrtf(tot);
        inv[tid] = iv;
        invn[(size_t)b * HW + m0 + tid] = iv;
    }
    __syncthreads();
    for (int r = 0; r < 16; ++r) {
        int idx = r * 256 + tid; int row = idx >> 6, c = idx & 63;
        float uv = T[c * 65 + row];
        XT[((size_t)b * HW + m0 + row) * C + c] = uv;
        float nv = uv * inv[row];
        unsigned u = __float_as_uint(nv);
        unsigned rr = u + 0x7fffu + ((u >> 16) & 1u);   // RNE to bf16
        Xhi[((size_t)b * HW + m0 + row) * C + c] = (unsigned short)(rr >> 16);
    }
}

// ---------------- kernel 1b: transpose W -> Wt[k][i][o] ----------------
__global__ void k_wt(const float* __restrict__ W, float* __restrict__ Wt) {
    int idx = blockIdx.x * 256 + threadIdx.x;
    if (idx < C * C * K) {
        int k = idx / (C * C);
        int rem = idx - k * (C * C);
        int i = rem >> 6, o = rem & 63;
        Wt[idx] = W[(o * C + i) * K + k];
    }
}

// ---------------- kernel 2: MFMA approx scores + branchless packed top-9 ----------------
// grid (72, NCH, BATCH), 256 threads (4 waves x 32 m each).
// key = (sortable_score & ~0x7FF) | (0x7FF - n_local)  -> umax ordering == (score desc, n asc)
__global__ __launch_bounds__(256) void k_score(const unsigned short* __restrict__ Xhi,
                                               unsigned* __restrict__ candi) {
    int mg = blockIdx.x, chunk = blockIdx.y, b = blockIdx.z;
    int tid = threadIdx.x;
    int w = tid >> 6, l = tid & 63;
    int lr = l & 31, lh = l >> 5;
    int m = mg * 128 + w * 32 + lr;
    const char* Xb = (const char*)(Xhi + (size_t)b * HW * C);   // 128B rows

    __shared__ __align__(16) char tiles[2][4096];

    bf16x8 bf[4];
#pragma unroll
    for (int t = 0; t < 4; ++t)
        bf[t] = *(const bf16x8*)(Xb + (size_t)m * 128 + t * 32 + lh * 16);

    int swsrc = (tid * 16) ^ (((tid >> 3) & 7) << 4);
    int nC = chunk * CHUNK;

    GLOAD_LDS(Xb + (size_t)nC * 128 + swsrc, &tiles[0][w * 1024]);
    __syncthreads();

    unsigned tv[9];
#pragma unroll
    for (int j = 0; j < 9; ++j) tv[j] = 0u;

    for (int s = 0; s < NSTEP; ++s) {
        if (s + 1 < NSTEP)
            GLOAD_LDS(Xb + (size_t)(nC + (s + 1) * 32) * 128 + swsrc,
                      &tiles[(s + 1) & 1][w * 1024]);
        const char* tile = tiles[s & 1];
        f32x16 acc = {0.f,0.f,0.f,0.f,0.f,0.f,0.f,0.f,0.f,0.f,0.f,0.f,0.f,0.f,0.f,0.f};
#pragma unroll
        for (int t = 0; t < 4; ++t) {
            int o = t * 32 + lh * 16;
            bf16x8 af = *(const bf16x8*)(tile + lr * 128 + (o ^ ((lr & 7) << 4)));
            acc = __builtin_amdgcn_mfma_f32_32x32x16_bf16(af, bf[t], acc, 0, 0, 0);
        }
        int nb_inv = 2047 - (s * 32 + 4 * lh);   // inverted local-index base
#pragma unroll
        for (int r = 0; r < 16; ++r) {
            unsigned u = __float_as_uint(acc[r]);
            unsigned sk = u ^ (unsigned)(((int)u >> 31) | 0x80000000);
            unsigned t0 = (sk & 0xFFFFF800u) | (unsigned)(nb_inv - ((r & 3) + 8 * (r >> 2)));
#pragma unroll
            for (int q = 0; q < 9; ++q) {
                unsigned hi = tv[q] >= t0 ? tv[q] : t0;
                unsigned lo = tv[q] >= t0 ? t0 : tv[q];
                tv[q] = hi; t0 = lo;
            }
        }
        __syncthreads();
    }

    // merge partner half-lane's sorted list (branchless inserts)
    unsigned otv[9];
#pragma unroll
    for (int j = 0; j < 9; ++j) otv[j] = tv[j];
#pragma unroll
    for (int j = 0; j < 9; ++j) {
        unsigned t0 = (unsigned)__shfl_xor((int)otv[j], 32, 64);
#pragma unroll
        for (int q = 0; q < 9; ++q) {
            unsigned hi = tv[q] >= t0 ? tv[q] : t0;
            unsigned lo = tv[q] >= t0 ? t0 : tv[q];
            tv[q] = hi; t0 = lo;
        }
    }
    if (lh == 0) {
        size_t base = ((size_t)(b * HW + m) * NCH + chunk) * 9;
#pragma unroll
        for (int j = 0; j < 9; ++j) candi[base + j] = tv[j];
    }
}

// ---------------- kernel 3: exact fp32 rescore of 72 candidates + top-7 ----------------
__global__ __launch_bounds__(256) void k_rescore(const float* __restrict__ XT,
                                                 const float* __restrict__ invn,
                                                 const unsigned* __restrict__ candi,
                                                 float* __restrict__ fvals,
                                                 int* __restrict__ fidx) {
    int g = blockIdx.x * 4 + (threadIdx.x >> 6);
    int l = threadIdx.x & 63;
    int b = g / HW, m = g - b * HW;
    const float* Xb = XT + (size_t)b * HW * C;
    const float4* xm = (const float4*)(Xb + (size_t)m * C);
    float vm = invn[g];

    float sv[2]; int si[2];
    {
        unsigned key = candi[(size_t)g * NCAND + l];
        int ci = (l / 9) * CHUNK + (2047 - (int)(key & 0x7FFu));
        const float4* xn = (const float4*)(Xb + (size_t)ci * C);
        float4 a = {0.f, 0.f, 0.f, 0.f};
#pragma unroll
        for (int c4 = 0; c4 < 16; ++c4) {
            float4 p = xm[c4], q = xn[c4];
            a.x += p.x * q.x; a.y += p.y * q.y; a.z += p.z * q.z; a.w += p.w * q.w;
        }
        sv[0] = (a.x + a.y + a.z + a.w) * vm * invn[(size_t)b * HW + ci];
        si[0] = ci;
    }
    if (l < 8) {
        unsigned key = candi[(size_t)g * NCAND + 64 + l];
        int ci = ((64 + l) / 9) * CHUNK + (2047 - (int)(key & 0x7FFu));
        const float4* xn = (const float4*)(Xb + (size_t)ci * C);
        float4 a = {0.f, 0.f, 0.f, 0.f};
#pragma unroll
        for (int c4 = 0; c4 < 16; ++c4) {
            float4 p = xm[c4], q = xn[c4];
            a.x += p.x * q.x; a.y += p.y * q.y; a.z += p.z * q.z; a.w += p.w * q.w;
        }
        sv[1] = (a.x + a.y + a.z + a.w) * vm * invn[(size_t)b * HW + ci];
        si[1] = ci;
    } else { sv[1] = -1e30f; si[1] = 0x7fffffff; }

    for (int s = 0; s < 7; ++s) {
        bool p0 = (sv[0] > sv[1]) || (sv[0] == sv[1] && si[0] < si[1]);
        float bv = p0 ? sv[0] : sv[1];
        int   bi = p0 ? si[0] : si[1];
#pragma unroll
        for (int d = 1; d < 64; d <<= 1) {
            float ov = __shfl_xor(bv, d, 64);
            int   oi = __shfl_xor(bi, d, 64);
            if (ov > bv || (ov == bv && oi < bi)) { bv = ov; bi = oi; }
        }
        if (l == 0) { fvals[(size_t)g * 7 + s] = bv; fidx[(size_t)g * 7 + s] = bi; }
        if (si[0] == bi) sv[0] = -1e30f;
        if (si[1] == bi) sv[1] = -1e30f;
    }
}

// ---------------- kernel 4: gather + conv contraction + bias + relu ----------------
__global__ __launch_bounds__(256) void k_out(const float* __restrict__ XT,
                                             const float* __restrict__ Wt,
                                             const float* __restrict__ fvals,
                                             const int* __restrict__ fidx,
                                             const float* __restrict__ bias,
                                             float* __restrict__ out) {
    int b = blockIdx.y;
    int m0 = blockIdx.x * 16;
    __shared__ float Wk[64 * 64];   // [i][o]
    __shared__ float Gw[16 * 64];   // [ml][i]
    int tid = threadIdx.x;
    int oq = tid & 15, ml = tid >> 4;
    float acc[4] = {0.f, 0.f, 0.f, 0.f};

    for (int k = 0; k < K; ++k) {
        __syncthreads();
        for (int r = 0; r < 16; ++r) Wk[r * 256 + tid] = Wt[k * 4096 + r * 256 + tid];
        {
            int pos = tid * 4;
            int m2 = pos >> 6, i0 = pos & 63;
            int gm = (b * HW + m0 + m2) * 7 + k;
            int n = fidx[gm];
            float vv = fvals[gm];
            float4 g = *(const float4*)&XT[((size_t)b * HW + n) * C + i0];
            float4 gw;
            gw.x = g.x * vv; gw.y = g.y * vv; gw.z = g.z * vv; gw.w = g.w * vv;
            *(float4*)&Gw[m2 * 64 + i0] = gw;
        }
        __syncthreads();
#pragma unroll 16
        for (int i = 0; i < 64; ++i) {
            float4 w = *(const float4*)&Wk[i * 64 + oq * 4];
            float g = Gw[ml * 64 + i];
            acc[0] += g * w.x; acc[1] += g * w.y; acc[2] += g * w.z; acc[3] += g * w.w;
        }
    }
    int m = m0 + ml;
#pragma unroll
    for (int j = 0; j < 4; ++j) {
        int o = oq * 4 + j;
        float v = acc[j] + bias[o];
        out[((size_t)b * C + o) * HW + m] = v > 0.f ? v : 0.f;
    }
}

extern "C" void kernel_launch(void* const* d_in, const int* in_sizes, int n_in,
                              void* d_out, int out_size, void* d_ws, size_t ws_size,
                              hipStream_t stream) {
    const float* x = (const float*)d_in[0];
    const float* W = (const float*)d_in[1];
    const float* bias = (const float*)d_in[2];
    float* out = (float*)d_out;

    float* ws = (float*)d_ws;
    float* XT = ws;                                        // B*HW*C
    unsigned short* Xhi = (unsigned short*)(XT + (size_t)BATCH * HW * C);   // B*HW*C bf16
    float* invn = (float*)(Xhi + (size_t)BATCH * HW * C);  // B*HW
    float* Wt = invn + (size_t)BATCH * HW;                 // K*C*C
    unsigned* candi = (unsigned*)(Wt + C * C * K);         // B*HW*NCAND packed keys
    float* fvals = (float*)(candi + (size_t)BATCH * HW * NCAND);
    int* fidx = (int*)(fvals + (size_t)BATCH * HW * K);

    k_norm<<<dim3(HW / 64, BATCH), 256, 0, stream>>>(x, XT, Xhi, invn);
    k_wt<<<dim3((C * C * K + 255) / 256), 256, 0, stream>>>(W, Wt);
    k_score<<<dim3(HW / 128, NCH, BATCH), 256, 0, stream>>>(Xhi, candi);
    k_rescore<<<dim3(BATCH * HW / 4), 256, 0, stream>>>(XT, invn, candi, fvals, fidx);
    k_out<<<dim3(HW / 16, BATCH), 256, 0, stream>>>(XT, Wt, fvals, fidx, bias, out);
}

// Round 4
// 259.562 us; speedup vs baseline: 2.6286x; 1.0172x over previous
//
#include <hip/hip_runtime.h>
#include <math.h>

#define HW 9216
#define C 64
#define BATCH 2
#define K 7
#define NCH 16
#define CHUNK 576            // HW/NCH
#define NSTEP 18             // CHUNK/32
#define LTOP 8               // per-chunk kept candidates
#define NCAND 128            // NCH*LTOP

typedef __attribute__((ext_vector_type(8))) short bf16x8;
typedef __attribute__((ext_vector_type(16))) float f32x16;

#define GLOAD_LDS(gp, lp) __builtin_amdgcn_global_load_lds( \
    (const __attribute__((address_space(1))) unsigned int*)(gp), \
    (__attribute__((address_space(3))) unsigned int*)(lp), 16, 0, 0)

// ---------------- kernel 1: normalize + transpose + bf16 ----------------
__global__ __launch_bounds__(256) void k_norm(const float* __restrict__ x,
                                              float* __restrict__ XT,
                                              unsigned short* __restrict__ Xhi,
                                              float* __restrict__ invn) {
    int b = blockIdx.y, m0 = blockIdx.x * 64, tid = threadIdx.x;
    __shared__ float T[64 * 65];
    __shared__ float ps[4][64];
    __shared__ float inv[64];
    const float* xb = x + (size_t)b * C * HW;
    for (int r = 0; r < 16; ++r) {
        int idx = r * 256 + tid; int c = idx >> 6, mm = idx & 63;
        T[c * 65 + mm] = xb[(size_t)c * HW + m0 + mm];
    }
    __syncthreads();
    int ml = tid & 63, part = tid >> 6;
    float s = 0.f;
    for (int c = part * 16; c < part * 16 + 16; ++c) { float v = T[c * 65 + ml]; s += v * v; }
    ps[part][ml] = s;
    __syncthreads();
    if (tid < 64) {
        float tot = ps[0][tid] + ps[1][tid] + ps[2][tid] + ps[3][tid];
        float iv = 1.0f / sqrtf(tot);
        inv[tid] = iv;
        invn[(size_t)b * HW + m0 + tid] = iv;
    }
    __syncthreads();
    for (int r = 0; r < 16; ++r) {
        int idx = r * 256 + tid; int row = idx >> 6, c = idx & 63;
        float uv = T[c * 65 + row];
        XT[((size_t)b * HW + m0 + row) * C + c] = uv;
        float nv = uv * inv[row];
        unsigned u = __float_as_uint(nv);
        unsigned rr = u + 0x7fffu + ((u >> 16) & 1u);   // RNE to bf16
        Xhi[((size_t)b * HW + m0 + row) * C + c] = (unsigned short)(rr >> 16);
    }
}

// ---------------- kernel 1b: transpose W -> Wt[k][i][o] ----------------
__global__ void k_wt(const float* __restrict__ W, float* __restrict__ Wt) {
    int idx = blockIdx.x * 256 + threadIdx.x;
    if (idx < C * C * K) {
        int k = idx / (C * C);
        int rem = idx - k * (C * C);
        int i = rem >> 6, o = rem & 63;
        Wt[idx] = W[(o * C + i) * K + k];
    }
}

// ---------------- kernel 2: MFMA approx scores + branchless packed top-8 ----------------
// grid (72, NCH, BATCH), 256 threads (4 waves x 32 m each).
// acc biased +1.0625 -> all positive -> raw float bits are monotone sortable.
// key = (bits & ~0x7FF) | (2047 - n_local)  -> umax == (score desc, n asc)
__global__ __launch_bounds__(256) void k_score(const unsigned short* __restrict__ Xhi,
                                               unsigned* __restrict__ candi) {
    int mg = blockIdx.x, chunk = blockIdx.y, b = blockIdx.z;
    int tid = threadIdx.x;
    int w = tid >> 6, l = tid & 63;
    int lr = l & 31, lh = l >> 5;
    int m = mg * 128 + w * 32 + lr;
    const char* Xb = (const char*)(Xhi + (size_t)b * HW * C);   // 128B rows

    __shared__ __align__(16) char tiles[2][4096];

    bf16x8 bf[4];
#pragma unroll
    for (int t = 0; t < 4; ++t)
        bf[t] = *(const bf16x8*)(Xb + (size_t)m * 128 + t * 32 + lh * 16);

    int swsrc = (tid * 16) ^ (((tid >> 3) & 7) << 4);
    int nC = chunk * CHUNK;

    GLOAD_LDS(Xb + (size_t)nC * 128 + swsrc, &tiles[0][w * 1024]);
    __syncthreads();

    unsigned tv[LTOP];
#pragma unroll
    for (int j = 0; j < LTOP; ++j) tv[j] = 0u;

    const float BIAS = 1.0625f;

    for (int s = 0; s < NSTEP; ++s) {
        if (s + 1 < NSTEP)
            GLOAD_LDS(Xb + (size_t)(nC + (s + 1) * 32) * 128 + swsrc,
                      &tiles[(s + 1) & 1][w * 1024]);
        const char* tile = tiles[s & 1];
        f32x16 acc = {BIAS,BIAS,BIAS,BIAS,BIAS,BIAS,BIAS,BIAS,
                      BIAS,BIAS,BIAS,BIAS,BIAS,BIAS,BIAS,BIAS};
#pragma unroll
        for (int t = 0; t < 4; ++t) {
            int o = t * 32 + lh * 16;
            bf16x8 af = *(const bf16x8*)(tile + lr * 128 + (o ^ ((lr & 7) << 4)));
            acc = __builtin_amdgcn_mfma_f32_32x32x16_bf16(af, bf[t], acc, 0, 0, 0);
        }
        unsigned inv_base = 2047u - (unsigned)(s * 32 + 4 * lh);
#pragma unroll
        for (int r = 0; r < 16; ++r) {
            unsigned t0 = (__float_as_uint(acc[r]) & 0xFFFFF800u)
                        | (inv_base - (unsigned)((r & 3) + 8 * (r >> 2)));
#pragma unroll
            for (int q = 0; q < LTOP; ++q) {
                unsigned hi = tv[q] >= t0 ? tv[q] : t0;
                unsigned lo = tv[q] >= t0 ? t0 : tv[q];
                tv[q] = hi; t0 = lo;
            }
        }
        __syncthreads();
    }

    // bitonic partial merge with partner half-lane: top8(A,B)[i] = max(A[i], B[7-i])
    unsigned pv[LTOP];
#pragma unroll
    for (int j = 0; j < LTOP; ++j) pv[j] = tv[j];
#pragma unroll
    for (int j = 0; j < LTOP; ++j) {
        unsigned o = (unsigned)__shfl_xor((int)pv[LTOP - 1 - j], 32, 64);
        tv[j] = tv[j] >= o ? tv[j] : o;
    }
    if (lh == 0) {
        size_t base = ((size_t)(b * HW + m) * NCH + chunk) * LTOP;
#pragma unroll
        for (int j = 0; j < LTOP; ++j) candi[base + j] = tv[j];
    }
}

// ---------------- kernel 3: exact fp32 rescore of 128 candidates + top-7 ----------------
// one wave per row; 2 candidates per lane
__global__ __launch_bounds__(256) void k_rescore(const float* __restrict__ XT,
                                                 const float* __restrict__ invn,
                                                 const unsigned* __restrict__ candi,
                                                 float* __restrict__ fvals,
                                                 int* __restrict__ fidx) {
    int g = blockIdx.x * 4 + (threadIdx.x >> 6);
    int l = threadIdx.x & 63;
    int b = g / HW, m = g - b * HW;
    const float* Xb = XT + (size_t)b * HW * C;
    const float4* xm = (const float4*)(Xb + (size_t)m * C);
    float vm = invn[g];

    float sv[2]; int si[2];
#pragma unroll
    for (int h = 0; h < 2; ++h) {
        int c = h * 64 + l;
        unsigned key = candi[(size_t)g * NCAND + c];
        int ci = (c >> 3) * CHUNK + (2047 - (int)(key & 0x7FFu));
        const float4* xn = (const float4*)(Xb + (size_t)ci * C);
        float4 a = {0.f, 0.f, 0.f, 0.f};
#pragma unroll
        for (int c4 = 0; c4 < 16; ++c4) {
            float4 p = xm[c4], q = xn[c4];
            a.x += p.x * q.x; a.y += p.y * q.y; a.z += p.z * q.z; a.w += p.w * q.w;
        }
        sv[h] = (a.x + a.y + a.z + a.w) * vm * invn[(size_t)b * HW + ci];
        si[h] = ci;
    }
    // dedupe guard: same candidate can't appear twice (distinct chunks), fine.

    for (int s = 0; s < 7; ++s) {
        bool p0 = (sv[0] > sv[1]) || (sv[0] == sv[1] && si[0] < si[1]);
        float bv = p0 ? sv[0] : sv[1];
        int   bi = p0 ? si[0] : si[1];
#pragma unroll
        for (int d = 1; d < 64; d <<= 1) {
            float ov = __shfl_xor(bv, d, 64);
            int   oi = __shfl_xor(bi, d, 64);
            if (ov > bv || (ov == bv && oi < bi)) { bv = ov; bi = oi; }
        }
        if (l == 0) { fvals[(size_t)g * 7 + s] = bv; fidx[(size_t)g * 7 + s] = bi; }
        if (si[0] == bi) sv[0] = -1e30f;
        if (si[1] == bi) sv[1] = -1e30f;
    }
}

// ---------------- kernel 4: gather + conv contraction + bias + relu ----------------
__global__ __launch_bounds__(256) void k_out(const float* __restrict__ XT,
                                             const float* __restrict__ Wt,
                                             const float* __restrict__ fvals,
                                             const int* __restrict__ fidx,
                                             const float* __restrict__ bias,
                                             float* __restrict__ out) {
    int b = blockIdx.y;
    int m0 = blockIdx.x * 16;
    __shared__ float Wk[64 * 64];   // [i][o]
    __shared__ float Gw[16 * 64];   // [ml][i]
    int tid = threadIdx.x;
    int oq = tid & 15, ml = tid >> 4;
    float acc[4] = {0.f, 0.f, 0.f, 0.f};

    for (int k = 0; k < K; ++k) {
        __syncthreads();
        for (int r = 0; r < 16; ++r) Wk[r * 256 + tid] = Wt[k * 4096 + r * 256 + tid];
        {
            int pos = tid * 4;
            int m2 = pos >> 6, i0 = pos & 63;
            int gm = (b * HW + m0 + m2) * 7 + k;
            int n = fidx[gm];
            float vv = fvals[gm];
            float4 g = *(const float4*)&XT[((size_t)b * HW + n) * C + i0];
            float4 gw;
            gw.x = g.x * vv; gw.y = g.y * vv; gw.z = g.z * vv; gw.w = g.w * vv;
            *(float4*)&Gw[m2 * 64 + i0] = gw;
        }
        __syncthreads();
#pragma unroll 16
        for (int i = 0; i < 64; ++i) {
            float4 w = *(const float4*)&Wk[i * 64 + oq * 4];
            float g = Gw[ml * 64 + i];
            acc[0] += g * w.x; acc[1] += g * w.y; acc[2] += g * w.z; acc[3] += g * w.w;
        }
    }
    int m = m0 + ml;
#pragma unroll
    for (int j = 0; j < 4; ++j) {
        int o = oq * 4 + j;
        float v = acc[j] + bias[o];
        out[((size_t)b * C + o) * HW + m] = v > 0.f ? v : 0.f;
    }
}

extern "C" void kernel_launch(void* const* d_in, const int* in_sizes, int n_in,
                              void* d_out, int out_size, void* d_ws, size_t ws_size,
                              hipStream_t stream) {
    const float* x = (const float*)d_in[0];
    const float* W = (const float*)d_in[1];
    const float* bias = (const float*)d_in[2];
    float* out = (float*)d_out;

    float* ws = (float*)d_ws;
    float* XT = ws;                                        // B*HW*C f32
    unsigned short* Xhi = (unsigned short*)(XT + (size_t)BATCH * HW * C);   // B*HW*C bf16
    float* invn = (float*)(Xhi + (size_t)BATCH * HW * C);  // B*HW
    float* Wt = invn + (size_t)BATCH * HW;                 // K*C*C
    unsigned* candi = (unsigned*)(Wt + C * C * K);         // B*HW*NCAND packed keys
    float* fvals = (float*)(candi + (size_t)BATCH * HW * NCAND);
    int* fidx = (int*)(fvals + (size_t)BATCH * HW * K);

    k_norm<<<dim3(HW / 64, BATCH), 256, 0, stream>>>(x, XT, Xhi, invn);
    k_wt<<<dim3((C * C * K + 255) / 256), 256, 0, stream>>>(W, Wt);
    k_score<<<dim3(HW / 128, NCH, BATCH), 256, 0, stream>>>(Xhi, candi);
    k_rescore<<<dim3(BATCH * HW / 4), 256, 0, stream>>>(XT, invn, candi, fvals, fidx);
    k_out<<<dim3(HW / 16, BATCH), 256, 0, stream>>>(XT, Wt, fvals, fidx, bias, out);
}

// Round 5
// 238.329 us; speedup vs baseline: 2.8628x; 1.0891x over previous
//
#include <hip/hip_runtime.h>
#include <math.h>

#define HW 9216
#define C 64
#define BATCH 2
#define K 7
#define NCH 16
#define CHUNK 576            // HW/NCH
#define NOUT 9               // outer steps, 64 rows each
#define LTOP 8               // per-chunk kept candidates
#define NCAND 128            // NCH*LTOP

typedef __attribute__((ext_vector_type(8))) short bf16x8;
typedef __attribute__((ext_vector_type(16))) float f32x16;

#define GLOAD_LDS(gp, lp) __builtin_amdgcn_global_load_lds( \
    (const __attribute__((address_space(1))) unsigned int*)(gp), \
    (__attribute__((address_space(3))) unsigned int*)(lp), 16, 0, 0)

// ---------------- kernel 1: normalize + transpose + bf16 ----------------
__global__ __launch_bounds__(256) void k_norm(const float* __restrict__ x,
                                              float* __restrict__ XT,
                                              unsigned short* __restrict__ Xhi,
                                              float* __restrict__ invn) {
    int b = blockIdx.y, m0 = blockIdx.x * 64, tid = threadIdx.x;
    __shared__ float T[64 * 65];
    __shared__ float ps[4][64];
    __shared__ float inv[64];
    const float* xb = x + (size_t)b * C * HW;
    for (int r = 0; r < 16; ++r) {
        int idx = r * 256 + tid; int c = idx >> 6, mm = idx & 63;
        T[c * 65 + mm] = xb[(size_t)c * HW + m0 + mm];
    }
    __syncthreads();
    int ml = tid & 63, part = tid >> 6;
    float s = 0.f;
    for (int c = part * 16; c < part * 16 + 16; ++c) { float v = T[c * 65 + ml]; s += v * v; }
    ps[part][ml] = s;
    __syncthreads();
    if (tid < 64) {
        float tot = ps[0][tid] + ps[1][tid] + ps[2][tid] + ps[3][tid];
        float iv = 1.0f / sqrtf(tot);
        inv[tid] = iv;
        invn[(size_t)b * HW + m0 + tid] = iv;
    }
    __syncthreads();
    for (int r = 0; r < 16; ++r) {
        int idx = r * 256 + tid; int row = idx >> 6, c = idx & 63;
        float uv = T[c * 65 + row];
        XT[((size_t)b * HW + m0 + row) * C + c] = uv;
        float nv = uv * inv[row];
        unsigned u = __float_as_uint(nv);
        unsigned rr = u + 0x7fffu + ((u >> 16) & 1u);   // RNE to bf16
        Xhi[((size_t)b * HW + m0 + row) * C + c] = (unsigned short)(rr >> 16);
    }
}

// ---------------- kernel 1b: transpose W -> Wt[k][i][o] ----------------
__global__ void k_wt(const float* __restrict__ W, float* __restrict__ Wt) {
    int idx = blockIdx.x * 256 + threadIdx.x;
    if (idx < C * C * K) {
        int k = idx / (C * C);
        int rem = idx - k * (C * C);
        int i = rem >> 6, o = rem & 63;
        Wt[idx] = W[(o * C + i) * K + k];
    }
}

// ---------------- kernel 2: MFMA approx scores + branchless packed top-8 ----------------
// grid (72, NCH, BATCH), 256 threads (4 waves x 32 m each). 64-row LDS tiles, 9 outer steps.
// acc biased +1.0625 -> all positive -> raw float bits are monotone sortable.
// key = (bits & ~0x7FF) | (2047 - n_local)  -> umax == (score desc, n asc)
__global__ __launch_bounds__(256) void k_score(const unsigned short* __restrict__ Xhi,
                                               unsigned* __restrict__ candi) {
    int mg = blockIdx.x, chunk = blockIdx.y, b = blockIdx.z;
    int tid = threadIdx.x;
    int w = tid >> 6, l = tid & 63;
    int lr = l & 31, lh = l >> 5;
    int m = mg * 128 + w * 32 + lr;
    const char* Xb = (const char*)(Xhi + (size_t)b * HW * C);   // 128B rows

    __shared__ __align__(16) char tiles[2][8192];

    bf16x8 bf[4];
#pragma unroll
    for (int t = 0; t < 4; ++t)
        bf[t] = *(const bf16x8*)(Xb + (size_t)m * 128 + t * 32 + lh * 16);

    int swsrc = (tid * 16) ^ (((tid >> 3) & 7) << 4);   // within first 4KB
    int nC = chunk * CHUNK;

    // prologue: stage 64-row tile 0 (two 4KB halves)
    GLOAD_LDS(Xb + (size_t)nC * 128 + swsrc, &tiles[0][w * 1024]);
    GLOAD_LDS(Xb + (size_t)nC * 128 + 4096 + swsrc, &tiles[0][4096 + w * 1024]);
    __syncthreads();

    unsigned tv[LTOP];
#pragma unroll
    for (int j = 0; j < LTOP; ++j) tv[j] = 0u;

    const float BIAS = 1.0625f;

    for (int so = 0; so < NOUT; ++so) {
        if (so + 1 < NOUT) {
            const char* src = Xb + (size_t)(nC + (so + 1) * 64) * 128;
            GLOAD_LDS(src + swsrc, &tiles[(so + 1) & 1][w * 1024]);
            GLOAD_LDS(src + 4096 + swsrc, &tiles[(so + 1) & 1][4096 + w * 1024]);
        }
        const char* tile = tiles[so & 1];
#pragma unroll
        for (int h = 0; h < 2; ++h) {
            f32x16 acc = {BIAS,BIAS,BIAS,BIAS,BIAS,BIAS,BIAS,BIAS,
                          BIAS,BIAS,BIAS,BIAS,BIAS,BIAS,BIAS,BIAS};
#pragma unroll
            for (int t = 0; t < 4; ++t) {
                int o = t * 32 + lh * 16;
                bf16x8 af = *(const bf16x8*)(tile + (h * 32 + lr) * 128 + (o ^ ((lr & 7) << 4)));
                acc = __builtin_amdgcn_mfma_f32_32x32x16_bf16(af, bf[t], acc, 0, 0, 0);
            }
            unsigned inv_base = 2047u - (unsigned)(so * 64 + h * 32 + 4 * lh);
#pragma unroll
            for (int r = 0; r < 16; ++r) {
                unsigned t0 = (__float_as_uint(acc[r]) & 0xFFFFF800u)
                            | (inv_base - (unsigned)((r & 3) + 8 * (r >> 2)));
#pragma unroll
                for (int q = 0; q < LTOP; ++q) {
                    unsigned hi = tv[q] >= t0 ? tv[q] : t0;
                    unsigned lo = tv[q] >= t0 ? t0 : tv[q];
                    tv[q] = hi; t0 = lo;
                }
            }
        }
        __syncthreads();   // drains stage(so+1) and finishes reads of buf[so&1]
    }

    // bitonic partial merge with partner half-lane: top8(A,B)[i] = max(A[i], B[7-i])
    unsigned pv[LTOP];
#pragma unroll
    for (int j = 0; j < LTOP; ++j) pv[j] = tv[j];
#pragma unroll
    for (int j = 0; j < LTOP; ++j) {
        unsigned o = (unsigned)__shfl_xor((int)pv[LTOP - 1 - j], 32, 64);
        tv[j] = tv[j] >= o ? tv[j] : o;
    }
    if (lh == 0) {
        size_t base = ((size_t)(b * HW + m) * NCH + chunk) * LTOP;
#pragma unroll
        for (int j = 0; j < LTOP; ++j) candi[base + j] = tv[j];
    }
}

// ---------------- kernel 3: exact fp32 rescore, 16 lanes per candidate ----------------
// one block per row; 4 waves x 4 candidates/step x 8 steps = 128 candidates
__global__ __launch_bounds__(256) void k_rescore(const float* __restrict__ XT,
                                                 const float* __restrict__ invn,
                                                 const unsigned* __restrict__ candi,
                                                 float* __restrict__ fvals,
                                                 int* __restrict__ fidx) {
    int g = blockIdx.x;                  // global row, 0..BATCH*HW-1
    int b = g / HW;
    int tid = threadIdx.x;
    int w = tid >> 6, l = tid & 63;
    int cl = l & 15, grp = l >> 4;
    __shared__ float sc[NCAND];
    __shared__ int   sidx[NCAND];

    const float* Xb = XT + (size_t)b * HW * C;
    float4 xm4 = *(const float4*)(XT + (size_t)g * C + cl * 4);
    float vm = invn[g];

#pragma unroll
    for (int st = 0; st < 8; ++st) {
        int c = w * 32 + st * 4 + grp;
        unsigned key = candi[(size_t)g * NCAND + c];
        int ci = (c >> 3) * CHUNK + (2047 - (int)(key & 0x7FFu));
        float4 q4 = *(const float4*)(Xb + (size_t)ci * C + cl * 4);
        float s = xm4.x * q4.x + xm4.y * q4.y + xm4.z * q4.z + xm4.w * q4.w;
        s += __shfl_xor(s, 1, 64);
        s += __shfl_xor(s, 2, 64);
        s += __shfl_xor(s, 4, 64);
        s += __shfl_xor(s, 8, 64);
        if (cl == 0) {
            sc[c] = s * vm * invn[(size_t)b * HW + ci];
            sidx[c] = ci;
        }
    }
    __syncthreads();
    if (w == 0) {
        float sv[2]; int si[2];
        sv[0] = sc[l];      si[0] = sidx[l];
        sv[1] = sc[64 + l]; si[1] = sidx[64 + l];
        for (int s = 0; s < 7; ++s) {
            bool p0 = (sv[0] > sv[1]) || (sv[0] == sv[1] && si[0] < si[1]);
            float bv = p0 ? sv[0] : sv[1];
            int   bi = p0 ? si[0] : si[1];
#pragma unroll
            for (int d = 1; d < 64; d <<= 1) {
                float ov = __shfl_xor(bv, d, 64);
                int   oi = __shfl_xor(bi, d, 64);
                if (ov > bv || (ov == bv && oi < bi)) { bv = ov; bi = oi; }
            }
            if (l == 0) { fvals[(size_t)g * 7 + s] = bv; fidx[(size_t)g * 7 + s] = bi; }
            if (si[0] == bi) sv[0] = -1e30f;
            if (si[1] == bi) sv[1] = -1e30f;
        }
    }
}

// ---------------- kernel 4: gather + conv contraction + bias + relu ----------------
// 16 m per block; single barrier; W read via L1/L2 broadcast loads
__global__ __launch_bounds__(256) void k_out(const float* __restrict__ XT,
                                             const float* __restrict__ Wt,
                                             const float* __restrict__ fvals,
                                             const int* __restrict__ fidx,
                                             const float* __restrict__ bias,
                                             float* __restrict__ out) {
    int b = blockIdx.y;
    int m0 = blockIdx.x * 16;
    __shared__ float Gw[7][16][64];   // 28 KB
    int tid = threadIdx.x;

    // gather all 7 k-slices: thread j-th slot = (k=j, m2=tid>>4, i0=(tid&15)*4)
#pragma unroll
    for (int j = 0; j < 7; ++j) {
        int m2 = tid >> 4, i0 = (tid & 15) * 4;
        int gm = (b * HW + m0 + m2) * 7 + j;
        int n = fidx[gm];
        float vv = fvals[gm];
        float4 g = *(const float4*)&XT[((size_t)b * HW + n) * C + i0];
        float4 gw;
        gw.x = g.x * vv; gw.y = g.y * vv; gw.z = g.z * vv; gw.w = g.w * vv;
        *(float4*)&Gw[j][m2][i0] = gw;
    }
    __syncthreads();

    int oq = tid & 15, ml = tid >> 4;
    float acc[4] = {0.f, 0.f, 0.f, 0.f};
#pragma unroll
    for (int k = 0; k < K; ++k) {
        const float* Wk = Wt + k * 4096;
#pragma unroll 4
        for (int i = 0; i < 64; i += 4) {
            float4 g4 = *(const float4*)&Gw[k][ml][i];
#pragma unroll
            for (int d = 0; d < 4; ++d) {
                float4 w4 = *(const float4*)&Wk[(i + d) * 64 + oq * 4];
                float gd = (d == 0) ? g4.x : (d == 1) ? g4.y : (d == 2) ? g4.z : g4.w;
                acc[0] += gd * w4.x; acc[1] += gd * w4.y;
                acc[2] += gd * w4.z; acc[3] += gd * w4.w;
            }
        }
    }
    int m = m0 + ml;
#pragma unroll
    for (int j = 0; j < 4; ++j) {
        int o = oq * 4 + j;
        float v = acc[j] + bias[o];
        out[((size_t)b * C + o) * HW + m] = v > 0.f ? v : 0.f;
    }
}

extern "C" void kernel_launch(void* const* d_in, const int* in_sizes, int n_in,
                              void* d_out, int out_size, void* d_ws, size_t ws_size,
                              hipStream_t stream) {
    const float* x = (const float*)d_in[0];
    const float* W = (const float*)d_in[1];
    const float* bias = (const float*)d_in[2];
    float* out = (float*)d_out;

    float* ws = (float*)d_ws;
    float* XT = ws;                                        // B*HW*C f32
    unsigned short* Xhi = (unsigned short*)(XT + (size_t)BATCH * HW * C);   // B*HW*C bf16
    float* invn = (float*)(Xhi + (size_t)BATCH * HW * C);  // B*HW
    float* Wt = invn + (size_t)BATCH * HW;                 // K*C*C
    unsigned* candi = (unsigned*)(Wt + C * C * K);         // B*HW*NCAND packed keys
    float* fvals = (float*)(candi + (size_t)BATCH * HW * NCAND);
    int* fidx = (int*)(fvals + (size_t)BATCH * HW * K);

    k_norm<<<dim3(HW / 64, BATCH), 256, 0, stream>>>(x, XT, Xhi, invn);
    k_wt<<<dim3((C * C * K + 255) / 256), 256, 0, stream>>>(W, Wt);
    k_score<<<dim3(HW / 128, NCH, BATCH), 256, 0, stream>>>(Xhi, candi);
    k_rescore<<<dim3(BATCH * HW), 256, 0, stream>>>(XT, invn, candi, fvals, fidx);
    k_out<<<dim3(HW / 16, BATCH), 256, 0, stream>>>(XT, Wt, fvals, fidx, bias, out);
}

// Round 6
// 186.577 us; speedup vs baseline: 3.6569x; 1.2774x over previous
//
#include <hip/hip_runtime.h>
#include <math.h>

#define HW 9216
#define C 64
#define BATCH 2
#define K 7
#define NCH 16
#define CHUNK 576            // HW/NCH
#define NOUT 9               // outer steps, 64 rows each
#define LTOP 8               // per-chunk kept candidates
#define NCAND 128            // NCH*LTOP

typedef __attribute__((ext_vector_type(8))) short bf16x8;
typedef __attribute__((ext_vector_type(16))) float f32x16;

#define GLOAD_LDS(gp, lp) __builtin_amdgcn_global_load_lds( \
    (const __attribute__((address_space(1))) unsigned int*)(gp), \
    (__attribute__((address_space(3))) unsigned int*)(lp), 16, 0, 0)

__device__ __forceinline__ unsigned umax_(unsigned a, unsigned b) { return a >= b ? a : b; }
__device__ __forceinline__ unsigned umin_(unsigned a, unsigned b) { return a >= b ? b : a; }

// Batcher odd-even sort-8, descending (max at lower index), 19 CE
__device__ __forceinline__ void sort8_desc(unsigned (&k)[8]) {
#define CE8(i, j) { unsigned hi = umax_(k[i], k[j]); unsigned lo = umin_(k[i], k[j]); k[i] = hi; k[j] = lo; }
    CE8(0,1) CE8(2,3) CE8(4,5) CE8(6,7)
    CE8(0,2) CE8(1,3) CE8(4,6) CE8(5,7)
    CE8(1,2) CE8(5,6)
    CE8(0,4) CE8(1,5) CE8(2,6) CE8(3,7)
    CE8(2,4) CE8(3,5)
    CE8(1,2) CE8(3,4) CE8(5,6)
#undef CE8
}

// tv (sorted desc) := top-8 of tv ∪ s (s sorted desc), sorted desc.
// reversed elementwise max -> bitonic (valley) -> 12-CE bitonic clean.
__device__ __forceinline__ void merge8_desc(unsigned (&tv)[8], const unsigned (&s)[8]) {
    unsigned t[8];
#pragma unroll
    for (int i = 0; i < 8; ++i) t[i] = umax_(tv[i], s[7 - i]);
#define CET(i, j) { unsigned hi = umax_(t[i], t[j]); unsigned lo = umin_(t[i], t[j]); t[i] = hi; t[j] = lo; }
    CET(0,4) CET(1,5) CET(2,6) CET(3,7)
    CET(0,2) CET(1,3) CET(4,6) CET(5,7)
    CET(0,1) CET(2,3) CET(4,5) CET(6,7)
#undef CET
#pragma unroll
    for (int i = 0; i < 8; ++i) tv[i] = t[i];
}

// ---------------- kernel 1: normalize + transpose + bf16 ----------------
__global__ __launch_bounds__(256) void k_norm(const float* __restrict__ x,
                                              float* __restrict__ XT,
                                              unsigned short* __restrict__ Xhi,
                                              float* __restrict__ invn) {
    int b = blockIdx.y, m0 = blockIdx.x * 64, tid = threadIdx.x;
    __shared__ float T[64 * 65];
    __shared__ float ps[4][64];
    __shared__ float inv[64];
    const float* xb = x + (size_t)b * C * HW;
    for (int r = 0; r < 16; ++r) {
        int idx = r * 256 + tid; int c = idx >> 6, mm = idx & 63;
        T[c * 65 + mm] = xb[(size_t)c * HW + m0 + mm];
    }
    __syncthreads();
    int ml = tid & 63, part = tid >> 6;
    float s = 0.f;
    for (int c = part * 16; c < part * 16 + 16; ++c) { float v = T[c * 65 + ml]; s += v * v; }
    ps[part][ml] = s;
    __syncthreads();
    if (tid < 64) {
        float tot = ps[0][tid] + ps[1][tid] + ps[2][tid] + ps[3][tid];
        float iv = 1.0f / sqrtf(tot);
        inv[tid] = iv;
        invn[(size_t)b * HW + m0 + tid] = iv;
    }
    __syncthreads();
    for (int r = 0; r < 16; ++r) {
        int idx = r * 256 + tid; int row = idx >> 6, c = idx & 63;
        float uv = T[c * 65 + row];
        XT[((size_t)b * HW + m0 + row) * C + c] = uv;
        float nv = uv * inv[row];
        unsigned u = __float_as_uint(nv);
        unsigned rr = u + 0x7fffu + ((u >> 16) & 1u);   // RNE to bf16
        Xhi[((size_t)b * HW + m0 + row) * C + c] = (unsigned short)(rr >> 16);
    }
}

// ---------------- kernel 1b: transpose W -> Wt[k][i][o] ----------------
__global__ void k_wt(const float* __restrict__ W, float* __restrict__ Wt) {
    int idx = blockIdx.x * 256 + threadIdx.x;
    if (idx < C * C * K) {
        int k = idx / (C * C);
        int rem = idx - k * (C * C);
        int i = rem >> 6, o = rem & 63;
        Wt[idx] = W[(o * C + i) * K + k];
    }
}

// ---------------- kernel 2: MFMA approx scores + batch sort-merge top-8 ----------------
// grid (72, NCH, BATCH), 256 threads (4 waves x 32 m each). 64-row LDS tiles, 9 outer steps.
// acc biased +1.0625 -> all positive -> raw float bits monotone sortable.
// key = (bits & ~0x7FF) | (2047 - n_local)  -> umax == (score desc, n asc)
__global__ __launch_bounds__(256) void k_score(const unsigned short* __restrict__ Xhi,
                                               unsigned* __restrict__ candi) {
    int mg = blockIdx.x, chunk = blockIdx.y, b = blockIdx.z;
    int tid = threadIdx.x;
    int w = tid >> 6, l = tid & 63;
    int lr = l & 31, lh = l >> 5;
    int m = mg * 128 + w * 32 + lr;
    const char* Xb = (const char*)(Xhi + (size_t)b * HW * C);   // 128B rows

    __shared__ __align__(16) char tiles[2][8192];

    bf16x8 bf[4];
#pragma unroll
    for (int t = 0; t < 4; ++t)
        bf[t] = *(const bf16x8*)(Xb + (size_t)m * 128 + t * 32 + lh * 16);

    int swsrc = (tid * 16) ^ (((tid >> 3) & 7) << 4);   // within first 4KB
    int nC = chunk * CHUNK;

    GLOAD_LDS(Xb + (size_t)nC * 128 + swsrc, &tiles[0][w * 1024]);
    GLOAD_LDS(Xb + (size_t)nC * 128 + 4096 + swsrc, &tiles[0][4096 + w * 1024]);
    __syncthreads();

    unsigned tv[LTOP];
#pragma unroll
    for (int j = 0; j < LTOP; ++j) tv[j] = 0u;

    const float BIAS = 1.0625f;

    for (int so = 0; so < NOUT; ++so) {
        if (so + 1 < NOUT) {
            const char* src = Xb + (size_t)(nC + (so + 1) * 64) * 128;
            GLOAD_LDS(src + swsrc, &tiles[(so + 1) & 1][w * 1024]);
            GLOAD_LDS(src + 4096 + swsrc, &tiles[(so + 1) & 1][4096 + w * 1024]);
        }
        const char* tile = tiles[so & 1];
#pragma unroll
        for (int h = 0; h < 2; ++h) {
            f32x16 acc = {BIAS,BIAS,BIAS,BIAS,BIAS,BIAS,BIAS,BIAS,
                          BIAS,BIAS,BIAS,BIAS,BIAS,BIAS,BIAS,BIAS};
#pragma unroll
            for (int t = 0; t < 4; ++t) {
                int o = t * 32 + lh * 16;
                bf16x8 af = *(const bf16x8*)(tile + (h * 32 + lr) * 128 + (o ^ ((lr & 7) << 4)));
                acc = __builtin_amdgcn_mfma_f32_32x32x16_bf16(af, bf[t], acc, 0, 0, 0);
            }
            unsigned inv_base = 2047u - (unsigned)(so * 64 + h * 32 + 4 * lh);
            unsigned ka[8], kb[8];
#pragma unroll
            for (int r = 0; r < 8; ++r) {
                ka[r] = (__float_as_uint(acc[r]) & 0xFFFFF800u)
                      | (inv_base - (unsigned)((r & 3) + 8 * (r >> 2)));
                kb[r] = (__float_as_uint(acc[r + 8]) & 0xFFFFF800u)
                      | (inv_base - (unsigned)(((r + 8) & 3) + 8 * ((r + 8) >> 2)));
            }
            sort8_desc(ka);
            sort8_desc(kb);
            merge8_desc(tv, ka);
            merge8_desc(tv, kb);
        }
        __syncthreads();   // drains stage(so+1); finishes reads of buf[so&1]
    }

    // bitonic partial merge with partner half-lane: top8(A,B)[i] = max(A[i], B[7-i])
    unsigned pv[LTOP];
#pragma unroll
    for (int j = 0; j < LTOP; ++j) pv[j] = tv[j];
#pragma unroll
    for (int j = 0; j < LTOP; ++j) {
        unsigned o = (unsigned)__shfl_xor((int)pv[LTOP - 1 - j], 32, 64);
        tv[j] = umax_(tv[j], o);
    }
    if (lh == 0) {
        size_t base = ((size_t)(b * HW + m) * NCH + chunk) * LTOP;
#pragma unroll
        for (int j = 0; j < LTOP; ++j) candi[base + j] = tv[j];
    }
}

// ---------------- kernel 3: threshold-pruned exact fp32 rescore ----------------
// one wave per row (4 rows/block). Approx 7th-largest key -> margin threshold ->
// exact-rescore only survivors (~8-12 of 128). Margin 0.012 > 2*(2^-8) + 2^-11.
__global__ __launch_bounds__(256) void k_rescore(const float* __restrict__ XT,
                                                 const float* __restrict__ invn,
                                                 const unsigned* __restrict__ candi,
                                                 float* __restrict__ fvals,
                                                 int* __restrict__ fidx) {
    int g = blockIdx.x * 4 + (threadIdx.x >> 6);
    int l = threadIdx.x & 63;
    int b = g / HW, m = g - b * HW;
    const float* Xb = XT + (size_t)b * HW * C;
    float xml = Xb[(size_t)m * C + l];
    float vm = invn[g];

    unsigned k0 = candi[(size_t)g * NCAND + l];
    unsigned k1 = candi[(size_t)g * NCAND + 64 + l];

    // 7 rounds of wave-max to find approx 7th-largest key
    unsigned c0 = k0, c1 = k1, kth = 0;
    for (int s = 0; s < 7; ++s) {
        unsigned mx = umax_(c0, c1);
#pragma unroll
        for (int d = 1; d < 64; d <<= 1)
            mx = umax_(mx, (unsigned)__shfl_xor((int)mx, d, 64));
        kth = mx;
        if (c0 == mx) c0 = 0u;
        else if (c1 == mx) c1 = 0u;
    }
    float s7 = __uint_as_float(kth & 0xFFFFF800u);
    unsigned thr = __float_as_uint(s7 - 0.012f) & 0xFFFFF800u;

    unsigned long long bal0 = __ballot(k0 >= thr);
    unsigned long long bal1 = __ballot(k1 >= thr);

    float svv = -1e30f; int svi = 0x7fffffff;
    int nsurv = 0;
#pragma unroll
    for (int h = 0; h < 2; ++h) {
        unsigned long long bb = h ? bal1 : bal0;
        while (bb) {
            int src = __builtin_ctzll(bb);
            bb &= bb - 1;
            unsigned key = (unsigned)__shfl((int)(h ? k1 : k0), src, 64);
            int cpos = h * 64 + src;
            int ci = (cpos >> 3) * CHUNK + (2047 - (int)(key & 0x7FFu));
            float v = xml * Xb[(size_t)ci * C + l];
            v += __shfl_xor(v, 1, 64);  v += __shfl_xor(v, 2, 64);
            v += __shfl_xor(v, 4, 64);  v += __shfl_xor(v, 8, 64);
            v += __shfl_xor(v, 16, 64); v += __shfl_xor(v, 32, 64);
            if (l == nsurv) { svv = v * vm * invn[(size_t)b * HW + ci]; svi = ci; }
            ++nsurv;
        }
    }

    // exact top-7 among survivors (value desc, index asc)
    for (int s = 0; s < 7; ++s) {
        float bv = svv; int bi = svi;
#pragma unroll
        for (int d = 1; d < 64; d <<= 1) {
            float ov = __shfl_xor(bv, d, 64);
            int   oi = __shfl_xor(bi, d, 64);
            if (ov > bv || (ov == bv && oi < bi)) { bv = ov; bi = oi; }
        }
        if (l == 0) { fvals[(size_t)g * 7 + s] = bv; fidx[(size_t)g * 7 + s] = bi; }
        if (svi == bi) svv = -1e30f;
    }
}

// ---------------- kernel 4: gather + conv contraction + bias + relu ----------------
__global__ __launch_bounds__(256) void k_out(const float* __restrict__ XT,
                                             const float* __restrict__ Wt,
                                             const float* __restrict__ fvals,
                                             const int* __restrict__ fidx,
                                             const float* __restrict__ bias,
                                             float* __restrict__ out) {
    int b = blockIdx.y;
    int m0 = blockIdx.x * 16;
    __shared__ float Gw[7][16][64];   // 28 KB
    int tid = threadIdx.x;

#pragma unroll
    for (int j = 0; j < 7; ++j) {
        int m2 = tid >> 4, i0 = (tid & 15) * 4;
        int gm = (b * HW + m0 + m2) * 7 + j;
        int n = fidx[gm];
        float vv = fvals[gm];
        float4 g = *(const float4*)&XT[((size_t)b * HW + n) * C + i0];
        float4 gw;
        gw.x = g.x * vv; gw.y = g.y * vv; gw.z = g.z * vv; gw.w = g.w * vv;
        *(float4*)&Gw[j][m2][i0] = gw;
    }
    __syncthreads();

    int oq = tid & 15, ml = tid >> 4;
    float acc[4] = {0.f, 0.f, 0.f, 0.f};
#pragma unroll
    for (int k = 0; k < K; ++k) {
        const float* Wk = Wt + k * 4096;
#pragma unroll 4
        for (int i = 0; i < 64; i += 4) {
            float4 g4 = *(const float4*)&Gw[k][ml][i];
#pragma unroll
            for (int d = 0; d < 4; ++d) {
                float4 w4 = *(const float4*)&Wk[(i + d) * 64 + oq * 4];
                float gd = (d == 0) ? g4.x : (d == 1) ? g4.y : (d == 2) ? g4.z : g4.w;
                acc[0] += gd * w4.x; acc[1] += gd * w4.y;
                acc[2] += gd * w4.z; acc[3] += gd * w4.w;
            }
        }
    }
    int m = m0 + ml;
#pragma unroll
    for (int j = 0; j < 4; ++j) {
        int o = oq * 4 + j;
        float v = acc[j] + bias[o];
        out[((size_t)b * C + o) * HW + m] = v > 0.f ? v : 0.f;
    }
}

extern "C" void kernel_launch(void* const* d_in, const int* in_sizes, int n_in,
                              void* d_out, int out_size, void* d_ws, size_t ws_size,
                              hipStream_t stream) {
    const float* x = (const float*)d_in[0];
    const float* W = (const float*)d_in[1];
    const float* bias = (const float*)d_in[2];
    float* out = (float*)d_out;

    float* ws = (float*)d_ws;
    float* XT = ws;                                        // B*HW*C f32
    unsigned short* Xhi = (unsigned short*)(XT + (size_t)BATCH * HW * C);   // B*HW*C bf16
    float* invn = (float*)(Xhi + (size_t)BATCH * HW * C);  // B*HW
    float* Wt = invn + (size_t)BATCH * HW;                 // K*C*C
    unsigned* candi = (unsigned*)(Wt + C * C * K);         // B*HW*NCAND packed keys
    float* fvals = (float*)(candi + (size_t)BATCH * HW * NCAND);
    int* fidx = (int*)(fvals + (size_t)BATCH * HW * K);

    k_norm<<<dim3(HW / 64, BATCH), 256, 0, stream>>>(x, XT, Xhi, invn);
    k_wt<<<dim3((C * C * K + 255) / 256), 256, 0, stream>>>(W, Wt);
    k_score<<<dim3(HW / 128, NCH, BATCH), 256, 0, stream>>>(Xhi, candi);
    k_rescore<<<dim3(BATCH * HW / 4), 256, 0, stream>>>(XT, invn, candi, fvals, fidx);
    k_out<<<dim3(HW / 16, BATCH), 256, 0, stream>>>(XT, Wt, fvals, fidx, bias, out);
}

// Round 7
// 143.687 us; speedup vs baseline: 4.7484x; 1.2985x over previous
//
#include <hip/hip_runtime.h>
#include <math.h>

#define HW 9216
#define C 64
#define BATCH 2
#define K 7
#define NCH 16
#define CHUNK 576            // HW/NCH
#define NOUT 9               // outer steps, 64 rows each
#define LTOP 8               // per-chunk kept candidates
#define NCAND 128            // NCH*LTOP
#define MB 8                 // m per k_out block

typedef __attribute__((ext_vector_type(8))) short bf16x8;
typedef __attribute__((ext_vector_type(16))) float f32x16;

#define GLOAD_LDS(gp, lp) __builtin_amdgcn_global_load_lds( \
    (const __attribute__((address_space(1))) unsigned int*)(gp), \
    (__attribute__((address_space(3))) unsigned int*)(lp), 16, 0, 0)

__device__ __forceinline__ unsigned umax_(unsigned a, unsigned b) {
#if defined(__has_builtin) && __has_builtin(__builtin_elementwise_max)
    return __builtin_elementwise_max(a, b);
#else
    return a >= b ? a : b;
#endif
}
__device__ __forceinline__ unsigned umin_(unsigned a, unsigned b) {
#if defined(__has_builtin) && __has_builtin(__builtin_elementwise_min)
    return __builtin_elementwise_min(a, b);
#else
    return a >= b ? b : a;
#endif
}

// Batcher odd-even sort-8, descending (max at lower index), 19 CE
__device__ __forceinline__ void sort8_desc(unsigned (&k)[8]) {
#define CE8(i, j) { unsigned hi = umax_(k[i], k[j]); unsigned lo = umin_(k[i], k[j]); k[i] = hi; k[j] = lo; }
    CE8(0,1) CE8(2,3) CE8(4,5) CE8(6,7)
    CE8(0,2) CE8(1,3) CE8(4,6) CE8(5,7)
    CE8(1,2) CE8(5,6)
    CE8(0,4) CE8(1,5) CE8(2,6) CE8(3,7)
    CE8(2,4) CE8(3,5)
    CE8(1,2) CE8(3,4) CE8(5,6)
#undef CE8
}

// tv (sorted desc) := top-8 of tv ∪ s (s sorted desc), sorted desc.
__device__ __forceinline__ void merge8_desc(unsigned (&tv)[8], const unsigned (&s)[8]) {
    unsigned t[8];
#pragma unroll
    for (int i = 0; i < 8; ++i) t[i] = umax_(tv[i], s[7 - i]);
#define CET(i, j) { unsigned hi = umax_(t[i], t[j]); unsigned lo = umin_(t[i], t[j]); t[i] = hi; t[j] = lo; }
    CET(0,4) CET(1,5) CET(2,6) CET(3,7)
    CET(0,2) CET(1,3) CET(4,6) CET(5,7)
    CET(0,1) CET(2,3) CET(4,5) CET(6,7)
#undef CET
#pragma unroll
    for (int i = 0; i < 8; ++i) tv[i] = t[i];
}

// ---------------- kernel 1: normalize + transpose + bf16 ----------------
__global__ __launch_bounds__(256) void k_norm(const float* __restrict__ x,
                                              float* __restrict__ XT,
                                              unsigned short* __restrict__ Xhi,
                                              float* __restrict__ invn) {
    int b = blockIdx.y, m0 = blockIdx.x * 64, tid = threadIdx.x;
    __shared__ float T[64 * 65];
    __shared__ float ps[4][64];
    __shared__ float inv[64];
    const float* xb = x + (size_t)b * C * HW;
    for (int r = 0; r < 16; ++r) {
        int idx = r * 256 + tid; int c = idx >> 6, mm = idx & 63;
        T[c * 65 + mm] = xb[(size_t)c * HW + m0 + mm];
    }
    __syncthreads();
    int ml = tid & 63, part = tid >> 6;
    float s = 0.f;
    for (int c = part * 16; c < part * 16 + 16; ++c) { float v = T[c * 65 + ml]; s += v * v; }
    ps[part][ml] = s;
    __syncthreads();
    if (tid < 64) {
        float tot = ps[0][tid] + ps[1][tid] + ps[2][tid] + ps[3][tid];
        float iv = 1.0f / sqrtf(tot);
        inv[tid] = iv;
        invn[(size_t)b * HW + m0 + tid] = iv;
    }
    __syncthreads();
    for (int r = 0; r < 16; ++r) {
        int idx = r * 256 + tid; int row = idx >> 6, c = idx & 63;
        float uv = T[c * 65 + row];
        XT[((size_t)b * HW + m0 + row) * C + c] = uv;
        float nv = uv * inv[row];
        unsigned u = __float_as_uint(nv);
        unsigned rr = u + 0x7fffu + ((u >> 16) & 1u);   // RNE to bf16
        Xhi[((size_t)b * HW + m0 + row) * C + c] = (unsigned short)(rr >> 16);
    }
}

// ---------------- kernel 1b: transpose W -> Wt[k][i][o] ----------------
__global__ void k_wt(const float* __restrict__ W, float* __restrict__ Wt) {
    int idx = blockIdx.x * 256 + threadIdx.x;
    if (idx < C * C * K) {
        int k = idx / (C * C);
        int rem = idx - k * (C * C);
        int i = rem >> 6, o = rem & 63;
        Wt[idx] = W[(o * C + i) * K + k];
    }
}

// ---------------- kernel 2: MFMA approx scores + batch sort-merge top-8 ----------------
__global__ __launch_bounds__(256) void k_score(const unsigned short* __restrict__ Xhi,
                                               unsigned* __restrict__ candi) {
    int mg = blockIdx.x, chunk = blockIdx.y, b = blockIdx.z;
    int tid = threadIdx.x;
    int w = tid >> 6, l = tid & 63;
    int lr = l & 31, lh = l >> 5;
    int m = mg * 128 + w * 32 + lr;
    const char* Xb = (const char*)(Xhi + (size_t)b * HW * C);   // 128B rows

    __shared__ __align__(16) char tiles[2][8192];

    bf16x8 bf[4];
#pragma unroll
    for (int t = 0; t < 4; ++t)
        bf[t] = *(const bf16x8*)(Xb + (size_t)m * 128 + t * 32 + lh * 16);

    int swsrc = (tid * 16) ^ (((tid >> 3) & 7) << 4);   // within first 4KB
    int nC = chunk * CHUNK;

    GLOAD_LDS(Xb + (size_t)nC * 128 + swsrc, &tiles[0][w * 1024]);
    GLOAD_LDS(Xb + (size_t)nC * 128 + 4096 + swsrc, &tiles[0][4096 + w * 1024]);
    __syncthreads();

    unsigned tv[LTOP];
#pragma unroll
    for (int j = 0; j < LTOP; ++j) tv[j] = 0u;

    const float BIAS = 1.0625f;

    for (int so = 0; so < NOUT; ++so) {
        if (so + 1 < NOUT) {
            const char* src = Xb + (size_t)(nC + (so + 1) * 64) * 128;
            GLOAD_LDS(src + swsrc, &tiles[(so + 1) & 1][w * 1024]);
            GLOAD_LDS(src + 4096 + swsrc, &tiles[(so + 1) & 1][4096 + w * 1024]);
        }
        const char* tile = tiles[so & 1];
#pragma unroll
        for (int h = 0; h < 2; ++h) {
            f32x16 acc = {BIAS,BIAS,BIAS,BIAS,BIAS,BIAS,BIAS,BIAS,
                          BIAS,BIAS,BIAS,BIAS,BIAS,BIAS,BIAS,BIAS};
#pragma unroll
            for (int t = 0; t < 4; ++t) {
                int o = t * 32 + lh * 16;
                bf16x8 af = *(const bf16x8*)(tile + (h * 32 + lr) * 128 + (o ^ ((lr & 7) << 4)));
                acc = __builtin_amdgcn_mfma_f32_32x32x16_bf16(af, bf[t], acc, 0, 0, 0);
            }
            unsigned inv_base = 2047u - (unsigned)(so * 64 + h * 32 + 4 * lh);
            unsigned ka[8], kb[8];
#pragma unroll
            for (int r = 0; r < 8; ++r) {
                ka[r] = (__float_as_uint(acc[r]) & 0xFFFFF800u)
                      | (inv_base - (unsigned)((r & 3) + 8 * (r >> 2)));
                kb[r] = (__float_as_uint(acc[r + 8]) & 0xFFFFF800u)
                      | (inv_base - (unsigned)(((r + 8) & 3) + 8 * ((r + 8) >> 2)));
            }
            sort8_desc(ka);
            sort8_desc(kb);
            merge8_desc(tv, ka);
            merge8_desc(tv, kb);
        }
        __syncthreads();
    }

    // bitonic partial merge with partner half-lane: top8(A,B)[i] = max(A[i], B[7-i])
    unsigned pv[LTOP];
#pragma unroll
    for (int j = 0; j < LTOP; ++j) pv[j] = tv[j];
#pragma unroll
    for (int j = 0; j < LTOP; ++j) {
        unsigned o = (unsigned)__shfl_xor((int)pv[LTOP - 1 - j], 32, 64);
        tv[j] = umax_(tv[j], o);
    }
    if (lh == 0) {
        size_t base = ((size_t)(b * HW + m) * NCH + chunk) * LTOP;
#pragma unroll
        for (int j = 0; j < LTOP; ++j) candi[base + j] = tv[j];
    }
}

// ---------------- kernel 3: threshold-pruned exact fp32 rescore ----------------
__global__ __launch_bounds__(256) void k_rescore(const float* __restrict__ XT,
                                                 const float* __restrict__ invn,
                                                 const unsigned* __restrict__ candi,
                                                 float* __restrict__ fvals,
                                                 int* __restrict__ fidx) {
    int g = blockIdx.x * 4 + (threadIdx.x >> 6);
    int l = threadIdx.x & 63;
    int b = g / HW, m = g - b * HW;
    const float* Xb = XT + (size_t)b * HW * C;
    float xml = Xb[(size_t)m * C + l];
    float vm = invn[g];

    unsigned k0 = candi[(size_t)g * NCAND + l];
    unsigned k1 = candi[(size_t)g * NCAND + 64 + l];

    // 7 rounds of wave-max to find approx 7th-largest key
    unsigned c0 = k0, c1 = k1, kth = 0;
    for (int s = 0; s < 7; ++s) {
        unsigned mx = umax_(c0, c1);
#pragma unroll
        for (int d = 1; d < 64; d <<= 1)
            mx = umax_(mx, (unsigned)__shfl_xor((int)mx, d, 64));
        kth = mx;
        if (c0 == mx) c0 = 0u;
        else if (c1 == mx) c1 = 0u;
    }
    float s7 = __uint_as_float(kth & 0xFFFFF800u);
    unsigned thr = __float_as_uint(s7 - 0.012f) & 0xFFFFF800u;

    unsigned long long bal0 = __ballot(k0 >= thr);
    unsigned long long bal1 = __ballot(k1 >= thr);

    float svv = -1e30f; int svi = 0x7fffffff;
    int nsurv = 0;
#pragma unroll
    for (int h = 0; h < 2; ++h) {
        unsigned long long bb = h ? bal1 : bal0;
        while (bb) {
            int src = __builtin_ctzll(bb);
            bb &= bb - 1;
            unsigned key = (unsigned)__shfl((int)(h ? k1 : k0), src, 64);
            int cpos = h * 64 + src;
            int ci = (cpos >> 3) * CHUNK + (2047 - (int)(key & 0x7FFu));
            float v = xml * Xb[(size_t)ci * C + l];
            v += __shfl_xor(v, 1, 64);  v += __shfl_xor(v, 2, 64);
            v += __shfl_xor(v, 4, 64);  v += __shfl_xor(v, 8, 64);
            v += __shfl_xor(v, 16, 64); v += __shfl_xor(v, 32, 64);
            if (l == nsurv) { svv = v * vm * invn[(size_t)b * HW + ci]; svi = ci; }
            ++nsurv;
        }
    }

    for (int s = 0; s < 7; ++s) {
        float bv = svv; int bi = svi;
#pragma unroll
        for (int d = 1; d < 64; d <<= 1) {
            float ov = __shfl_xor(bv, d, 64);
            int   oi = __shfl_xor(bi, d, 64);
            if (ov > bv || (ov == bv && oi < bi)) { bv = ov; bi = oi; }
        }
        if (l == 0) { fvals[(size_t)g * 7 + s] = bv; fidx[(size_t)g * 7 + s] = bi; }
        if (svi == bi) svv = -1e30f;
    }
}

// ---------------- kernel 4: gather + conv + bias + relu, sub-split over ik ----------------
// block = 8 m; 256 threads = 16 oq x 16 sub; each thread: 28 W-float4 loads, 896 FMA
__global__ __launch_bounds__(256) void k_out(const float* __restrict__ XT,
                                             const float* __restrict__ Wt,
                                             const float* __restrict__ fvals,
                                             const int* __restrict__ fidx,
                                             const float* __restrict__ bias,
                                             float* __restrict__ out) {
    int b = blockIdx.y;
    int m0 = blockIdx.x * MB;
    __shared__ float Gw[K][MB][68];    // 15.2 KB
    __shared__ float Red[4][MB][68];   // 8.7 KB  [wave][m][o]
    int tid = threadIdx.x;

    // phase 1: gather 56 rows (8m x 7k), 16 threads per row
#pragma unroll
    for (int t = 0; t < 4; ++t) {
        int slot = t * 256 + tid;              // 1024 slots, 896 used
        if (slot < K * MB * 16) {
            int k = slot >> 7;                 // slot / 128
            int rem = slot & 127;
            int m2 = rem >> 4, i4 = rem & 15;
            int gm = (b * HW + m0 + m2) * 7 + k;
            int n = fidx[gm];
            float vv = fvals[gm];
            float4 g = *(const float4*)&XT[((size_t)b * HW + n) * C + i4 * 4];
            float4 gw = {g.x * vv, g.y * vv, g.z * vv, g.w * vv};
            *(float4*)&Gw[k][m2][i4 * 4] = gw;
        }
    }
    __syncthreads();

    // phase 2: thread (oq, sub) accumulates over i in [sub*4, sub*4+4), all k
    int oq = tid & 15, sub = tid >> 4;
    float acc[MB][4] = {};
#pragma unroll
    for (int k = 0; k < K; ++k) {
        const float* Wk = Wt + k * 4096;
#pragma unroll
        for (int j = 0; j < 4; ++j) {
            int i = sub * 4 + j;
            float4 w4 = *(const float4*)&Wk[i * 64 + oq * 4];
#pragma unroll
            for (int m = 0; m < MB; ++m) {
                float g = Gw[k][m][i];
                acc[m][0] += g * w4.x; acc[m][1] += g * w4.y;
                acc[m][2] += g * w4.z; acc[m][3] += g * w4.w;
            }
        }
    }

    // phase 3a: in-wave reduce across the wave's 4 subs (lanes ^16, ^32)
#pragma unroll
    for (int m = 0; m < MB; ++m)
#pragma unroll
        for (int j = 0; j < 4; ++j) {
            acc[m][j] += __shfl_xor(acc[m][j], 16, 64);
            acc[m][j] += __shfl_xor(acc[m][j], 32, 64);
        }
    int w = tid >> 6, l = tid & 63;
    if (l < 16) {
#pragma unroll
        for (int m = 0; m < MB; ++m)
            *(float4*)&Red[w][m][l * 4] = *(const float4*)&acc[m][0];
    }
    __syncthreads();

    // phase 3b: final sum over 4 waves + bias + relu; m fastest for coalescing
#pragma unroll
    for (int t = 0; t < 2; ++t) {
        int oidx = t * 256 + tid;              // 512 outputs = 8m x 64o
        int m = oidx & 7, o = (oidx >> 3) & 63;
        float v = Red[0][m][o] + Red[1][m][o] + Red[2][m][o] + Red[3][m][o] + bias[o];
        out[((size_t)b * C + o) * HW + m0 + m] = v > 0.f ? v : 0.f;
    }
}

extern "C" void kernel_launch(void* const* d_in, const int* in_sizes, int n_in,
                              void* d_out, int out_size, void* d_ws, size_t ws_size,
                              hipStream_t stream) {
    const float* x = (const float*)d_in[0];
    const float* W = (const float*)d_in[1];
    const float* bias = (const float*)d_in[2];
    float* out = (float*)d_out;

    float* ws = (float*)d_ws;
    float* XT = ws;                                        // B*HW*C f32
    unsigned short* Xhi = (unsigned short*)(XT + (size_t)BATCH * HW * C);   // B*HW*C bf16
    float* invn = (float*)(Xhi + (size_t)BATCH * HW * C);  // B*HW
    float* Wt = invn + (size_t)BATCH * HW;                 // K*C*C
    unsigned* candi = (unsigned*)(Wt + C * C * K);         // B*HW*NCAND packed keys
    float* fvals = (float*)(candi + (size_t)BATCH * HW * NCAND);
    int* fidx = (int*)(fvals + (size_t)BATCH * HW * K);

    k_norm<<<dim3(HW / 64, BATCH), 256, 0, stream>>>(x, XT, Xhi, invn);
    k_wt<<<dim3((C * C * K + 255) / 256), 256, 0, stream>>>(W, Wt);
    k_score<<<dim3(HW / 128, NCH, BATCH), 256, 0, stream>>>(Xhi, candi);
    k_rescore<<<dim3(BATCH * HW / 4), 256, 0, stream>>>(XT, invn, candi, fvals, fidx);
    k_out<<<dim3(HW / MB, BATCH), 256, 0, stream>>>(XT, Wt, fvals, fidx, bias, out);
}